// Round 18
// baseline (113.906 us; speedup 1.0000x reference)
//
#include <hip/hip_runtime.h>
#include <hip/hip_bf16.h>

typedef unsigned short bf16_t;
typedef __attribute__((ext_vector_type(8))) short bf16x8;
typedef __attribute__((ext_vector_type(4))) short bf16x4;
typedef __attribute__((ext_vector_type(4))) float f32x4;

#define MFMA16(a, b, c) __builtin_amdgcn_mfma_f32_16x16x32_bf16((a), (b), (c), 0, 0, 0)

__device__ __forceinline__ bf16_t f2bf(float f) {
  union { float f; unsigned u; } v; v.f = f;
  unsigned u = v.u;
  u += 0x7FFFu + ((u >> 16) & 1u);
  return (bf16_t)(u >> 16);
}

// packed fp32x2 -> bf16x2 (RNE), one VALU op
__device__ __forceinline__ unsigned cvt_pk_bf16(float lo, float hi) {
  unsigned r;
  asm volatile("v_cvt_pk_bf16_f32 %0, %1, %2" : "=v"(r) : "v"(lo), "v"(hi));
  return r;
}

__device__ __forceinline__ unsigned pack2(short lo, short hi) {
  return ((unsigned)(unsigned short)lo) | ((unsigned)(unsigned short)hi << 16);
}

__device__ __forceinline__ void gld_lds16(const void* g, void* l) {
  __builtin_amdgcn_global_load_lds(
      (const __attribute__((address_space(1))) unsigned int*)g,
      (__attribute__((address_space(3))) unsigned int*)l, 16, 0, 0);
}

// ---------------- elementwise fp32 -> bf16 (8/thread) ----------------
__global__ __launch_bounds__(256) void k_f32_to_bf16(const float* __restrict__ in,
                                                     bf16_t* __restrict__ out, int n8) {
  int i = blockIdx.x * 256 + threadIdx.x;
  if (i >= n8) return;
  const float4* p = (const float4*)in + (size_t)i * 2;
  float4 a = p[0], b = p[1];
  bf16x8 o;
  o[0] = (short)f2bf(a.x); o[1] = (short)f2bf(a.y); o[2] = (short)f2bf(a.z); o[3] = (short)f2bf(a.w);
  o[4] = (short)f2bf(b.x); o[5] = (short)f2bf(b.y); o[6] = (short)f2bf(b.z); o[7] = (short)f2bf(b.w);
  *((bf16x8*)out + i) = o;
}

// ---------------- transpose + convert: W[K][N] f32 -> Wt[N][K] bf16 ----------------
__global__ __launch_bounds__(256) void k_transpose_bf16(const float* __restrict__ W,
                                                        bf16_t* __restrict__ Wt, int K, int N) {
  __shared__ bf16_t t[64][65];
  int n0 = blockIdx.x * 64, k0 = blockIdx.y * 64;
  int tid = threadIdx.x;
#pragma unroll
  for (int p = 0; p < 16; ++p) {
    int lin = p * 256 + tid;
    int r = lin >> 6, c = lin & 63;
    t[r][c] = f2bf(W[(size_t)(k0 + r) * N + n0 + c]);
  }
  __syncthreads();
#pragma unroll
  for (int p = 0; p < 16; ++p) {
    int lin = p * 256 + tid;
    int nr = lin >> 6, kc = lin & 63;
    Wt[(size_t)(n0 + nr) * K + k0 + kc] = t[kc][nr];
  }
}

// ---------------- GEMM-BT (m97 structure), 1-D grid + XCD swizzle, BM/BN/TPB templated ----------------
// TPB=256: 4 waves 2x2. TPB=512: 8 waves 2x4 — same tile/L2 pattern, double the
// resident waves/SIMD. R15 lesson: keep BM>=128 when B-panel (6MB) > per-XCD L2.
template <bool BF16OUT, bool SCALEQ, int BM, int BN, int TPB>
__global__ __launch_bounds__(TPB) void k_gemm_bt(const bf16_t* __restrict__ A,
                                                 const bf16_t* __restrict__ Bt,
                                                 const float* __restrict__ bias,
                                                 void* __restrict__ Cout, int M, int N, int K,
                                                 int nx) {
  constexpr int WN = (TPB == 512) ? 4 : 2;   // waves along N
  constexpr int WM = (TPB / 64) / WN;        // waves along M (=2)
  constexpr int WTM = BM / WM;               // wave tile rows
  constexpr int WTN = BN / WN;               // wave tile cols
  constexpr int NI = WTM / 16;
  constexpr int NJ = WTN / 16;
  constexpr int PA = BM * 4 / TPB;           // A staging passes (16B/thread each)
  constexpr int PB = BN * 4 / TPB;
  __shared__ bf16_t Al[BM * 32];
  __shared__ bf16_t Bl[BN * 32];
  const int tid = threadIdx.x;
  const int lane = tid & 63;
  const int wid = tid >> 6;
  const int wm = wid / WN, wn = wid % WN;
  const int nwg = gridDim.x;
  const int cpx = nwg >> 3;
  const int swz = (blockIdx.x & 7) * cpx + (blockIdx.x >> 3);
  const int m0 = (swz / nx) * BM, n0 = (swz % nx) * BN;
  const int lr = lane & 15;
  const int lk = lane >> 4;

  f32x4 acc[NI][NJ] = {};

  for (int k0 = 0; k0 < K; k0 += 32) {
    __syncthreads();
#pragma unroll
    for (int p = 0; p < PA; ++p) {
      int o = p * TPB * 16 + tid * 16;
      int row = o >> 6, cb = o & 63;
      gld_lds16((const char*)A + ((size_t)(m0 + row) * K + k0) * 2 + cb, (char*)Al + o);
    }
#pragma unroll
    for (int p = 0; p < PB; ++p) {
      int o = p * TPB * 16 + tid * 16;
      int row = o >> 6, cb = o & 63;
      gld_lds16((const char*)Bt + ((size_t)(n0 + row) * K + k0) * 2 + cb, (char*)Bl + o);
    }
    __syncthreads();
    bf16x8 af[NI], bfr[NJ];
#pragma unroll
    for (int i = 0; i < NI; ++i)
      af[i] = *(const bf16x8*)(Al + ((wm * WTM + i * 16 + lr) * 32 + lk * 8));
#pragma unroll
    for (int j = 0; j < NJ; ++j)
      bfr[j] = *(const bf16x8*)(Bl + ((wn * WTN + j * 16 + lr) * 32 + lk * 8));
#pragma unroll
    for (int i = 0; i < NI; ++i)
#pragma unroll
      for (int j = 0; j < NJ; ++j)
        acc[i][j] = MFMA16(af[i], bfr[j], acc[i][j]);
  }

#pragma unroll
  for (int i = 0; i < NI; ++i) {
    int grow = m0 + wm * WTM + i * 16 + lk * 4;
#pragma unroll
    for (int j = 0; j < NJ; ++j) {
      int gcol = n0 + wn * WTN + j * 16 + lr;
      float bv = bias[gcol];
      float scl = (SCALEQ && gcol < 1024) ? 0.18033688011112042f : 1.0f;
#pragma unroll
      for (int r = 0; r < 4; ++r) {
        float v = (acc[i][j][r] + bv) * scl;
        size_t off = (size_t)(grow + r) * N + gcol;
        if (BF16OUT)
          ((bf16_t*)Cout)[off] = f2bf(v);
        else
          ((float*)Cout)[off] = v;
      }
    }
  }
}

// ---------------- fused causal attention (swapped QK^T, K via LDS, static softmax) ----------------
// R13/R14-verified STEP. R18: BALANCED QUARTET qt mapping. All 1024 blocks are
// co-resident (4/CU exactly) so dispatch ORDER doesn't matter — only the SUM of
// steps per CU quartet {flat, flat+256, flat+512, flat+768} does. Monotone
// qt=31-flat/32 gave quartet sums 80..52 (21% tail, occupancy sagged to 26%).
// New mapping per dispatch-group g=flat>>5: g<8: 31-g; g<16: 15-(g-8);
// g<24: 16+(g-16); else g-24 — every quartet sums to 62 steps (+4 prologues),
// bijective over qt∈{0..31}.
__global__ __launch_bounds__(256) void k_attn(const bf16_t* __restrict__ qkv,
                                              bf16_t* __restrict__ score) {
  __shared__ bf16_t Kl[2][64 * 64];  // [buf][kv-row][chunk'] 16 KiB, swizzled chunks
  __shared__ bf16_t Vt[2][64 * 64];  // [buf][d][kv] swizzled, 16 KiB
  __shared__ bf16_t Pl[4][16 * 64];  // per-wave P [q][kv] swizzled, 8 KiB
  const int tid = threadIdx.x;
  const int lane = tid & 63;
  const int w = tid >> 6;
  const int lr = lane & 15, lk = lane >> 4;

  const int flat = blockIdx.x;
  const int g = flat >> 5;
  const int idx = g & 7;
  const int grp = g >> 3;
  const int qt = (grp == 0) ? (31 - idx)
               : (grp == 1) ? (15 - idx)
               : (grp == 2) ? (16 + idx)
                            : idx;  // balanced quartets: sums 62 per CU
  const int bh = flat & 31;
  const int b = bh >> 4, h = bh & 15;

  const bf16_t* Qb = qkv + (size_t)b * 2048 * 3072 + h * 64;
  const bf16_t* Kb = Qb + 1024;
  const bf16_t* Vb = Qb + 2048;

  // V staging coords: pass p, thread t: e=p*256+t; d0=(e&15)*4 (4 d's), kv=2*(e>>4)
  // K staging coords: thread t2 stages global chunk (t2&7)^(row&7) of row t2>>3
  int d0c[2], kv2[2], krow[2], kchk[2];
#pragma unroll
  for (int p = 0; p < 2; ++p) {
    int e = p * 256 + tid;
    d0c[p] = (e & 15) * 4;
    kv2[p] = (e >> 4) * 2;
    krow[p] = e >> 3;
    kchk[p] = (e & 7) ^ (krow[p] & 7);
  }

  const int qr0 = qt * 64 + w * 16;
  const int q = qr0 + lr;  // this lane's q-row (swapped layout)
  const int jtEnd = qt + 1;

  // hoist Q fragments (pre-scaled by 1/sqrt(64)*log2e in the GEMM)
  bf16x8 qf[2];
#pragma unroll
  for (int ks = 0; ks < 2; ++ks)
    qf[ks] = *(const bf16x8*)(Qb + (size_t)(qr0 + lr) * 3072 + ks * 32 + lk * 8);

  f32x4 o[4] = {};
  float l = 0.f;

  // prologue: V(0)->Vt buf0 via regs (paired-kv b32 writes)
  {
    bf16x4 v0[2][2];
#pragma unroll
    for (int p = 0; p < 2; ++p) {
      v0[p][0] = *(const bf16x4*)(Vb + (size_t)kv2[p] * 3072 + d0c[p]);
      v0[p][1] = *(const bf16x4*)(Vb + (size_t)(kv2[p] + 1) * 3072 + d0c[p]);
    }
#pragma unroll
    for (int p = 0; p < 2; ++p)
#pragma unroll
      for (int j = 0; j < 4; ++j) {
        int d = d0c[p] + j;
        int addr = (d * 128 + kv2[p] * 2) ^ (((d & 7) ^ ((d >> 3) & 7)) << 4);
        *(unsigned*)((char*)Vt + addr) = pack2(v0[p][0][j], v0[p][1][j]);
      }
  }
  // prefetch V(1) regs, then issue K(0) gld_lds (order matters for vmcnt counts)
  bf16x4 vrA[2][2], vrB[2][2];
#pragma unroll
  for (int p = 0; p < 2; ++p) {
    vrA[p][0] = *(const bf16x4*)(Vb + (size_t)(64 + kv2[p]) * 3072 + d0c[p]);
    vrA[p][1] = *(const bf16x4*)(Vb + (size_t)(64 + kv2[p] + 1) * 3072 + d0c[p]);
  }
#pragma unroll
  for (int p = 0; p < 2; ++p)
    gld_lds16((const char*)Kb + ((size_t)krow[p] * 3072 + kchk[p] * 8) * 2,
              (char*)Kl + (p * 256 + tid) * 16);

  auto STEP = [&](int jt, bf16x4 (&vrC)[2][2], bf16x4 (&vrN)[2][2], bool last) {
    const int kv0 = jt * 64;
    // one barrier/step: prev-step LDS traffic drained (lgkm only; vmem in flight)
    asm volatile("s_waitcnt lgkmcnt(0)" ::: "memory");
    __builtin_amdgcn_s_barrier();
    // write V(jt+1) from regs into Vt buf[(jt+1)&1]: paired-kv b32
    char* wbase = (char*)Vt + (((jt + 1) & 1) << 13);
#pragma unroll
    for (int p = 0; p < 2; ++p)
#pragma unroll
      for (int j = 0; j < 4; ++j) {
        int d = d0c[p] + j;
        int addr = (d * 128 + kv2[p] * 2) ^ (((d & 7) ^ ((d >> 3) & 7)) << 4);
        *(unsigned*)(wbase + addr) = pack2(vrC[p][0][j], vrC[p][1][j]);
      }
    if (!last) {
      // prefetch V(jt+2) regs (4 loads), then K(jt+1) -> Kl buf[(jt+1)&1]
      const int kvV = (kv0 + 128 < 2048) ? kv0 + 128 : 1920;
#pragma unroll
      for (int p = 0; p < 2; ++p) {
        vrN[p][0] = *(const bf16x4*)(Vb + (size_t)(kvV + kv2[p]) * 3072 + d0c[p]);
        vrN[p][1] = *(const bf16x4*)(Vb + (size_t)(kvV + kv2[p] + 1) * 3072 + d0c[p]);
      }
      char* kbase = (char*)Kl + (((jt + 1) & 1) << 13);
#pragma unroll
      for (int p = 0; p < 2; ++p)
        gld_lds16((const char*)Kb + ((size_t)(kv0 + 64 + krow[p]) * 3072 + kchk[p] * 8) * 2,
                  kbase + (p * 256 + tid) * 16);
      // drain this step's K (2 oldest); keep 4 V + 2 K just issued in flight
      asm volatile("s_waitcnt vmcnt(6)" ::: "memory");
    } else {
      asm volatile("s_waitcnt vmcnt(0)" ::: "memory");
    }
    // K fragments from swizzled LDS buf[jt&1]
    const char* kread = (const char*)Kl + ((jt & 1) << 13);
    bf16x8 kf[4][2];
#pragma unroll
    for (int nc = 0; nc < 4; ++nc) {
      const char* rowp = kread + (nc * 16 + lr) * 128;
      kf[nc][0] = *(const bf16x8*)(rowp + ((lk ^ (lr & 7)) << 4));
      kf[nc][1] = *(const bf16x8*)(rowp + (((4 | lk) ^ (lr & 7)) << 4));
    }
    // S^T = K Q^T (swapped): s[nc][r] is (q=qr0+lr, kv=kv0+nc*16+lk*4+r)
    f32x4 s[4];
    __builtin_amdgcn_s_setprio(1);
#pragma unroll
    for (int nc = 0; nc < 4; ++nc) {
      f32x4 z = {};
      z = MFMA16(kf[nc][0], qf[0], z);
      z = MFMA16(kf[nc][1], qf[1], z);
      s[nc] = z;
    }
    __builtin_amdgcn_s_setprio(0);
    // causal mask (last tile of this wave only); exp2(-inf) = 0 below
    if (kv0 + 63 > qr0) {
#pragma unroll
      for (int nc = 0; nc < 4; ++nc)
#pragma unroll
        for (int r = 0; r < 4; ++r) {
          int kvi = kv0 + nc * 16 + lk * 4 + r;
          if (kvi > q) s[nc][r] = -INFINITY;
        }
    }
    // static softmax (base-2, no max subtraction); per-lane partial l
#pragma unroll
    for (int nc = 0; nc < 4; ++nc)
#pragma unroll
      for (int r = 0; r < 4; ++r) {
        float p = exp2f(s[nc][r]);
        s[nc][r] = p;
        l += p;
      }
    // P -> per-wave LDS: cvt_pk pairs packed into b64 writes
    bf16_t* Pw = Pl[w];
#pragma unroll
    for (int nc = 0; nc < 4; ++nc) {
      uint2 u;
      u.x = cvt_pk_bf16(s[nc][0], s[nc][1]);
      u.y = cvt_pk_bf16(s[nc][2], s[nc][3]);
      int addr = (lr * 128 + (nc * 16 + lk * 4) * 2) ^ ((lr & 7) << 4);
      *(uint2*)((char*)Pw + addr) = u;
    }
    // PV (swapped): o[db] += mfma(V^T-frag, P-frag) -> O^T (row=d, col=q)
    const char* rbase = (const char*)Vt + ((jt & 1) << 13);
    bf16x8 pa[2];
#pragma unroll
    for (int ks = 0; ks < 2; ++ks) {
      int addr = (lr * 128 + ks * 64 + lk * 16) ^ ((lr & 7) << 4);
      pa[ks] = *(const bf16x8*)((const char*)Pl[w] + addr);
    }
    __builtin_amdgcn_s_setprio(1);
#pragma unroll
    for (int db = 0; db < 4; ++db)
#pragma unroll
      for (int ks = 0; ks < 2; ++ks) {
        int d = db * 16 + lr;
        int addr = (d * 128 + ks * 64 + lk * 16) ^ (((d & 7) ^ ((d >> 3) & 7)) << 4);
        bf16x8 vb = *(const bf16x8*)(rbase + addr);
        o[db] = MFMA16(vb, pa[ks], o[db]);
      }
    __builtin_amdgcn_s_setprio(0);
  };

  int jt = 0;
  for (;;) {
    STEP(jt, vrA, vrB, jt + 1 == jtEnd);
    if (++jt == jtEnd) break;
    STEP(jt, vrB, vrA, jt + 1 == jtEnd);
    if (++jt == jtEnd) break;
  }

  // epilogue: cross-lane sum of l (lanes lr, lr+16, lr+32, lr+48 share q-row);
  // lane writes its q-row, d = db*16 + lk*4 + r (packed 8B stores)
  l += __shfl_xor(l, 16);
  l += __shfl_xor(l, 32);
  const float rl = 1.0f / l;
  bf16_t* orow = score + (size_t)(b * 2048 + q) * 1024 + h * 64 + lk * 4;
#pragma unroll
  for (int db = 0; db < 4; ++db) {
    unsigned w0 = cvt_pk_bf16(o[db][0] * rl, o[db][1] * rl);
    unsigned w1 = cvt_pk_bf16(o[db][2] * rl, o[db][3] * rl);
    uint2 pkt; pkt.x = w0; pkt.y = w1;
    *(uint2*)(orow + db * 16) = pkt;
  }
}

extern "C" void kernel_launch(void* const* d_in, const int* in_sizes, int n_in,
                              void* d_out, int out_size, void* d_ws, size_t ws_size,
                              hipStream_t stream) {
  const float* X  = (const float*)d_in[0];  // [2,2048,1024]
  const float* Wa = (const float*)d_in[1];  // [1024,3072]
  const float* ba = (const float*)d_in[2];  // [3072]
  const float* Wp = (const float*)d_in[3];  // [1024,1024]
  const float* bp = (const float*)d_in[4];  // [1024]
  float* out = (float*)d_out;               // [2,2048,1024] fp32

  char* ws = (char*)d_ws;
  bf16_t* Xb  = (bf16_t*)ws;                          // 8 MiB (reused as score)
  bf16_t* WaT = (bf16_t*)(ws + (size_t)(8u << 20));   // 6 MiB: W_attn^T [3072][1024]
  bf16_t* WpT = (bf16_t*)(ws + (size_t)(14u << 20));  // 2 MiB: W_proj^T [1024][1024]
  bf16_t* QKV = (bf16_t*)(ws + (size_t)(16u << 20));  // 24 MiB: [4096][3072]
  bf16_t* S_  = Xb;

  k_f32_to_bf16<<<2048, 256, 0, stream>>>(X, Xb, 4096 * 1024 / 8);
  k_transpose_bf16<<<dim3(48, 16), 256, 0, stream>>>(Wa, WaT, 1024, 3072);
  k_transpose_bf16<<<dim3(16, 16), 256, 0, stream>>>(Wp, WpT, 1024, 1024);
  // QKV: 128x128 tile, 512 threads (8 waves 2x4) -> 768 blocks = 3/CU = 6 waves/SIMD
  k_gemm_bt<true, true, 128, 128, 512><<<768, 512, 0, stream>>>(Xb, WaT, ba, QKV, 4096, 3072, 1024, 24);
  k_attn<<<1024, 256, 0, stream>>>(QKV, S_);
  // proj: 64x64 tile, 256 threads -> 1024 blocks = 4/CU (B=2MB L2-resident; R15 win)
  k_gemm_bt<false, false, 64, 64, 256><<<1024, 256, 0, stream>>>(S_, WpT, bp, out, 4096, 1024, 1024, 16);
}

// Round 19
// 113.367 us; speedup vs baseline: 1.0048x; 1.0048x over previous
//
#include <hip/hip_runtime.h>
#include <hip/hip_bf16.h>

typedef unsigned short bf16_t;
typedef __attribute__((ext_vector_type(8))) short bf16x8;
typedef __attribute__((ext_vector_type(4))) short bf16x4;
typedef __attribute__((ext_vector_type(4))) float f32x4;

#define MFMA16(a, b, c) __builtin_amdgcn_mfma_f32_16x16x32_bf16((a), (b), (c), 0, 0, 0)

__device__ __forceinline__ bf16_t f2bf(float f) {
  union { float f; unsigned u; } v; v.f = f;
  unsigned u = v.u;
  u += 0x7FFFu + ((u >> 16) & 1u);
  return (bf16_t)(u >> 16);
}

// packed fp32x2 -> bf16x2 (RNE), one VALU op
__device__ __forceinline__ unsigned cvt_pk_bf16(float lo, float hi) {
  unsigned r;
  asm volatile("v_cvt_pk_bf16_f32 %0, %1, %2" : "=v"(r) : "v"(lo), "v"(hi));
  return r;
}

__device__ __forceinline__ unsigned pack2(short lo, short hi) {
  return ((unsigned)(unsigned short)lo) | ((unsigned)(unsigned short)hi << 16);
}

__device__ __forceinline__ void gld_lds16(const void* g, void* l) {
  __builtin_amdgcn_global_load_lds(
      (const __attribute__((address_space(1))) unsigned int*)g,
      (__attribute__((address_space(3))) unsigned int*)l, 16, 0, 0);
}

// ---------------- elementwise fp32 -> bf16 (8/thread) ----------------
__global__ __launch_bounds__(256) void k_f32_to_bf16(const float* __restrict__ in,
                                                     bf16_t* __restrict__ out, int n8) {
  int i = blockIdx.x * 256 + threadIdx.x;
  if (i >= n8) return;
  const float4* p = (const float4*)in + (size_t)i * 2;
  float4 a = p[0], b = p[1];
  bf16x8 o;
  o[0] = (short)f2bf(a.x); o[1] = (short)f2bf(a.y); o[2] = (short)f2bf(a.z); o[3] = (short)f2bf(a.w);
  o[4] = (short)f2bf(b.x); o[5] = (short)f2bf(b.y); o[6] = (short)f2bf(b.z); o[7] = (short)f2bf(b.w);
  *((bf16x8*)out + i) = o;
}

// ---------------- transpose + convert: W[K][N] f32 -> Wt[N][K] bf16 ----------------
__global__ __launch_bounds__(256) void k_transpose_bf16(const float* __restrict__ W,
                                                        bf16_t* __restrict__ Wt, int K, int N) {
  __shared__ bf16_t t[64][65];
  int n0 = blockIdx.x * 64, k0 = blockIdx.y * 64;
  int tid = threadIdx.x;
#pragma unroll
  for (int p = 0; p < 16; ++p) {
    int lin = p * 256 + tid;
    int r = lin >> 6, c = lin & 63;
    t[r][c] = f2bf(W[(size_t)(k0 + r) * N + n0 + c]);
  }
  __syncthreads();
#pragma unroll
  for (int p = 0; p < 16; ++p) {
    int lin = p * 256 + tid;
    int nr = lin >> 6, kc = lin & 63;
    Wt[(size_t)(n0 + nr) * K + k0 + kc] = t[kc][nr];
  }
}

// ---------------- GEMM-BT, 2-phase double-buffered pipeline (T3-minimal) ----------------
// R19: LDS double-buffer + counted-drain pipeline replaces the m97 serial schedule
// (whose full vmcnt drain between stage and compute exposed global->LDS latency
// every K-step). Per iter: issue STAGE(next buf) -> ds_read/MFMA(cur buf) ->
// vmcnt(0) -> raw s_barrier. Stage latency hides under compute + 6 waves/SIMD TLP.
// Race-safe: end-of-iter barrier orders lagging waves' MFMA-forced lgkm completion
// before the next iter's overwrite of their read buffer.
// TPB=512: 8 waves 2x4 (QKV). TPB=256: 4 waves 2x2 (proj).
// R15 lesson: keep BM>=128 when B-panel (6MB) > per-XCD L2.
template <bool BF16OUT, bool SCALEQ, int BM, int BN, int TPB>
__global__ __launch_bounds__(TPB) void k_gemm_bt(const bf16_t* __restrict__ A,
                                                 const bf16_t* __restrict__ Bt,
                                                 const float* __restrict__ bias,
                                                 void* __restrict__ Cout, int M, int N, int K,
                                                 int nx) {
  constexpr int WN = (TPB == 512) ? 4 : 2;   // waves along N
  constexpr int WM = (TPB / 64) / WN;        // waves along M (=2)
  constexpr int WTM = BM / WM;               // wave tile rows
  constexpr int WTN = BN / WN;               // wave tile cols
  constexpr int NI = WTM / 16;
  constexpr int NJ = WTN / 16;
  constexpr int PA = BM * 4 / TPB;           // A staging passes (16B/thread each)
  constexpr int PB = BN * 4 / TPB;
  __shared__ bf16_t Al[2][BM * 32];
  __shared__ bf16_t Bl[2][BN * 32];
  const int tid = threadIdx.x;
  const int lane = tid & 63;
  const int wid = tid >> 6;
  const int wm = wid / WN, wn = wid % WN;
  const int nwg = gridDim.x;
  const int cpx = nwg >> 3;
  const int swz = (blockIdx.x & 7) * cpx + (blockIdx.x >> 3);
  const int m0 = (swz / nx) * BM, n0 = (swz % nx) * BN;
  const int lr = lane & 15;
  const int lk = lane >> 4;

  f32x4 acc[NI][NJ] = {};

  auto STAGE = [&](int buf, int k0) {
#pragma unroll
    for (int p = 0; p < PA; ++p) {
      int o = p * TPB * 16 + tid * 16;
      int row = o >> 6, cb = o & 63;
      gld_lds16((const char*)A + ((size_t)(m0 + row) * K + k0) * 2 + cb,
                (char*)Al[buf] + o);
    }
#pragma unroll
    for (int p = 0; p < PB; ++p) {
      int o = p * TPB * 16 + tid * 16;
      int row = o >> 6, cb = o & 63;
      gld_lds16((const char*)Bt + ((size_t)(n0 + row) * K + k0) * 2 + cb,
                (char*)Bl[buf] + o);
    }
  };

  // prologue: stage tile 0, drain, barrier
  STAGE(0, 0);
  asm volatile("s_waitcnt vmcnt(0)" ::: "memory");
  __builtin_amdgcn_s_barrier();

  const int nk = K >> 5;
  for (int t = 0; t < nk; ++t) {
    const int cur = t & 1;
    if (t + 1 < nk) STAGE(cur ^ 1, (t + 1) << 5);
    bf16x8 af[NI], bfr[NJ];
#pragma unroll
    for (int i = 0; i < NI; ++i)
      af[i] = *(const bf16x8*)(Al[cur] + ((wm * WTM + i * 16 + lr) * 32 + lk * 8));
#pragma unroll
    for (int j = 0; j < NJ; ++j)
      bfr[j] = *(const bf16x8*)(Bl[cur] + ((wn * WTN + j * 16 + lr) * 32 + lk * 8));
#pragma unroll
    for (int i = 0; i < NI; ++i)
#pragma unroll
      for (int j = 0; j < NJ; ++j)
        acc[i][j] = MFMA16(af[i], bfr[j], acc[i][j]);
    // drain this iter's stage (had compute to hide under), then buffer-swap barrier
    asm volatile("s_waitcnt vmcnt(0)" ::: "memory");
    __builtin_amdgcn_s_barrier();
  }

#pragma unroll
  for (int i = 0; i < NI; ++i) {
    int grow = m0 + wm * WTM + i * 16 + lk * 4;
#pragma unroll
    for (int j = 0; j < NJ; ++j) {
      int gcol = n0 + wn * WTN + j * 16 + lr;
      float bv = bias[gcol];
      float scl = (SCALEQ && gcol < 1024) ? 0.18033688011112042f : 1.0f;
#pragma unroll
      for (int r = 0; r < 4; ++r) {
        float v = (acc[i][j][r] + bv) * scl;
        size_t off = (size_t)(grow + r) * N + gcol;
        if (BF16OUT)
          ((bf16_t*)Cout)[off] = f2bf(v);
        else
          ((float*)Cout)[off] = v;
      }
    }
  }
}

// ---------------- fused causal attention (swapped QK^T, K via LDS, static softmax) ----------------
// Parked after three neutral rounds (latency-chain-bound at ~50us). 1024 blocks,
// one q-tile each (R18 balanced-quartet qt mapping, harmless); 4 waves x 16 q-rows;
// K staged once/block via global_load_lds (double-buffered, inverse-swizzled source
// + T2-swizzled b128 reads); Vt double-buffered via reg ping-pong (one raw
// barrier/step); counted vmcnt; swapped MFMAs; static softmax (no max subtraction;
// |s| <~ 6 bounded); packed epilogue.
__global__ __launch_bounds__(256) void k_attn(const bf16_t* __restrict__ qkv,
                                              bf16_t* __restrict__ score) {
  __shared__ bf16_t Kl[2][64 * 64];  // [buf][kv-row][chunk'] 16 KiB, swizzled chunks
  __shared__ bf16_t Vt[2][64 * 64];  // [buf][d][kv] swizzled, 16 KiB
  __shared__ bf16_t Pl[4][16 * 64];  // per-wave P [q][kv] swizzled, 8 KiB
  const int tid = threadIdx.x;
  const int lane = tid & 63;
  const int w = tid >> 6;
  const int lr = lane & 15, lk = lane >> 4;

  const int flat = blockIdx.x;
  const int g = flat >> 5;
  const int idx = g & 7;
  const int grp = g >> 3;
  const int qt = (grp == 0) ? (31 - idx)
               : (grp == 1) ? (15 - idx)
               : (grp == 2) ? (16 + idx)
                            : idx;  // balanced quartets
  const int bh = flat & 31;
  const int b = bh >> 4, h = bh & 15;

  const bf16_t* Qb = qkv + (size_t)b * 2048 * 3072 + h * 64;
  const bf16_t* Kb = Qb + 1024;
  const bf16_t* Vb = Qb + 2048;

  // V staging coords: pass p, thread t: e=p*256+t; d0=(e&15)*4 (4 d's), kv=2*(e>>4)
  // K staging coords: thread t2 stages global chunk (t2&7)^(row&7) of row t2>>3
  int d0c[2], kv2[2], krow[2], kchk[2];
#pragma unroll
  for (int p = 0; p < 2; ++p) {
    int e = p * 256 + tid;
    d0c[p] = (e & 15) * 4;
    kv2[p] = (e >> 4) * 2;
    krow[p] = e >> 3;
    kchk[p] = (e & 7) ^ (krow[p] & 7);
  }

  const int qr0 = qt * 64 + w * 16;
  const int q = qr0 + lr;  // this lane's q-row (swapped layout)
  const int jtEnd = qt + 1;

  // hoist Q fragments (pre-scaled by 1/sqrt(64)*log2e in the GEMM)
  bf16x8 qf[2];
#pragma unroll
  for (int ks = 0; ks < 2; ++ks)
    qf[ks] = *(const bf16x8*)(Qb + (size_t)(qr0 + lr) * 3072 + ks * 32 + lk * 8);

  f32x4 o[4] = {};
  float l = 0.f;

  // prologue: V(0)->Vt buf0 via regs (paired-kv b32 writes)
  {
    bf16x4 v0[2][2];
#pragma unroll
    for (int p = 0; p < 2; ++p) {
      v0[p][0] = *(const bf16x4*)(Vb + (size_t)kv2[p] * 3072 + d0c[p]);
      v0[p][1] = *(const bf16x4*)(Vb + (size_t)(kv2[p] + 1) * 3072 + d0c[p]);
    }
#pragma unroll
    for (int p = 0; p < 2; ++p)
#pragma unroll
      for (int j = 0; j < 4; ++j) {
        int d = d0c[p] + j;
        int addr = (d * 128 + kv2[p] * 2) ^ (((d & 7) ^ ((d >> 3) & 7)) << 4);
        *(unsigned*)((char*)Vt + addr) = pack2(v0[p][0][j], v0[p][1][j]);
      }
  }
  // prefetch V(1) regs, then issue K(0) gld_lds (order matters for vmcnt counts)
  bf16x4 vrA[2][2], vrB[2][2];
#pragma unroll
  for (int p = 0; p < 2; ++p) {
    vrA[p][0] = *(const bf16x4*)(Vb + (size_t)(64 + kv2[p]) * 3072 + d0c[p]);
    vrA[p][1] = *(const bf16x4*)(Vb + (size_t)(64 + kv2[p] + 1) * 3072 + d0c[p]);
  }
#pragma unroll
  for (int p = 0; p < 2; ++p)
    gld_lds16((const char*)Kb + ((size_t)krow[p] * 3072 + kchk[p] * 8) * 2,
              (char*)Kl + (p * 256 + tid) * 16);

  auto STEP = [&](int jt, bf16x4 (&vrC)[2][2], bf16x4 (&vrN)[2][2], bool last) {
    const int kv0 = jt * 64;
    // one barrier/step: prev-step LDS traffic drained (lgkm only; vmem in flight)
    asm volatile("s_waitcnt lgkmcnt(0)" ::: "memory");
    __builtin_amdgcn_s_barrier();
    // write V(jt+1) from regs into Vt buf[(jt+1)&1]: paired-kv b32
    char* wbase = (char*)Vt + (((jt + 1) & 1) << 13);
#pragma unroll
    for (int p = 0; p < 2; ++p)
#pragma unroll
      for (int j = 0; j < 4; ++j) {
        int d = d0c[p] + j;
        int addr = (d * 128 + kv2[p] * 2) ^ (((d & 7) ^ ((d >> 3) & 7)) << 4);
        *(unsigned*)(wbase + addr) = pack2(vrC[p][0][j], vrC[p][1][j]);
      }
    if (!last) {
      // prefetch V(jt+2) regs (4 loads), then K(jt+1) -> Kl buf[(jt+1)&1]
      const int kvV = (kv0 + 128 < 2048) ? kv0 + 128 : 1920;
#pragma unroll
      for (int p = 0; p < 2; ++p) {
        vrN[p][0] = *(const bf16x4*)(Vb + (size_t)(kvV + kv2[p]) * 3072 + d0c[p]);
        vrN[p][1] = *(const bf16x4*)(Vb + (size_t)(kvV + kv2[p] + 1) * 3072 + d0c[p]);
      }
      char* kbase = (char*)Kl + (((jt + 1) & 1) << 13);
#pragma unroll
      for (int p = 0; p < 2; ++p)
        gld_lds16((const char*)Kb + ((size_t)(kv0 + 64 + krow[p]) * 3072 + kchk[p] * 8) * 2,
                  kbase + (p * 256 + tid) * 16);
      // drain this step's K (2 oldest); keep 4 V + 2 K just issued in flight
      asm volatile("s_waitcnt vmcnt(6)" ::: "memory");
    } else {
      asm volatile("s_waitcnt vmcnt(0)" ::: "memory");
    }
    // K fragments from swizzled LDS buf[jt&1]
    const char* kread = (const char*)Kl + ((jt & 1) << 13);
    bf16x8 kf[4][2];
#pragma unroll
    for (int nc = 0; nc < 4; ++nc) {
      const char* rowp = kread + (nc * 16 + lr) * 128;
      kf[nc][0] = *(const bf16x8*)(rowp + ((lk ^ (lr & 7)) << 4));
      kf[nc][1] = *(const bf16x8*)(rowp + (((4 | lk) ^ (lr & 7)) << 4));
    }
    // S^T = K Q^T (swapped): s[nc][r] is (q=qr0+lr, kv=kv0+nc*16+lk*4+r)
    f32x4 s[4];
    __builtin_amdgcn_s_setprio(1);
#pragma unroll
    for (int nc = 0; nc < 4; ++nc) {
      f32x4 z = {};
      z = MFMA16(kf[nc][0], qf[0], z);
      z = MFMA16(kf[nc][1], qf[1], z);
      s[nc] = z;
    }
    __builtin_amdgcn_s_setprio(0);
    // causal mask (last tile of this wave only); exp2(-inf) = 0 below
    if (kv0 + 63 > qr0) {
#pragma unroll
      for (int nc = 0; nc < 4; ++nc)
#pragma unroll
        for (int r = 0; r < 4; ++r) {
          int kvi = kv0 + nc * 16 + lk * 4 + r;
          if (kvi > q) s[nc][r] = -INFINITY;
        }
    }
    // static softmax (base-2, no max subtraction); per-lane partial l
#pragma unroll
    for (int nc = 0; nc < 4; ++nc)
#pragma unroll
      for (int r = 0; r < 4; ++r) {
        float p = exp2f(s[nc][r]);
        s[nc][r] = p;
        l += p;
      }
    // P -> per-wave LDS: cvt_pk pairs packed into b64 writes
    bf16_t* Pw = Pl[w];
#pragma unroll
    for (int nc = 0; nc < 4; ++nc) {
      uint2 u;
      u.x = cvt_pk_bf16(s[nc][0], s[nc][1]);
      u.y = cvt_pk_bf16(s[nc][2], s[nc][3]);
      int addr = (lr * 128 + (nc * 16 + lk * 4) * 2) ^ ((lr & 7) << 4);
      *(uint2*)((char*)Pw + addr) = u;
    }
    // PV (swapped): o[db] += mfma(V^T-frag, P-frag) -> O^T (row=d, col=q)
    const char* rbase = (const char*)Vt + ((jt & 1) << 13);
    bf16x8 pa[2];
#pragma unroll
    for (int ks = 0; ks < 2; ++ks) {
      int addr = (lr * 128 + ks * 64 + lk * 16) ^ ((lr & 7) << 4);
      pa[ks] = *(const bf16x8*)((const char*)Pl[w] + addr);
    }
    __builtin_amdgcn_s_setprio(1);
#pragma unroll
    for (int db = 0; db < 4; ++db)
#pragma unroll
      for (int ks = 0; ks < 2; ++ks) {
        int d = db * 16 + lr;
        int addr = (d * 128 + ks * 64 + lk * 16) ^ (((d & 7) ^ ((d >> 3) & 7)) << 4);
        bf16x8 vb = *(const bf16x8*)(rbase + addr);
        o[db] = MFMA16(vb, pa[ks], o[db]);
      }
    __builtin_amdgcn_s_setprio(0);
  };

  int jt = 0;
  for (;;) {
    STEP(jt, vrA, vrB, jt + 1 == jtEnd);
    if (++jt == jtEnd) break;
    STEP(jt, vrB, vrA, jt + 1 == jtEnd);
    if (++jt == jtEnd) break;
  }

  // epilogue: cross-lane sum of l (lanes lr, lr+16, lr+32, lr+48 share q-row);
  // lane writes its q-row, d = db*16 + lk*4 + r (packed 8B stores)
  l += __shfl_xor(l, 16);
  l += __shfl_xor(l, 32);
  const float rl = 1.0f / l;
  bf16_t* orow = score + (size_t)(b * 2048 + q) * 1024 + h * 64 + lk * 4;
#pragma unroll
  for (int db = 0; db < 4; ++db) {
    unsigned w0 = cvt_pk_bf16(o[db][0] * rl, o[db][1] * rl);
    unsigned w1 = cvt_pk_bf16(o[db][2] * rl, o[db][3] * rl);
    uint2 pkt; pkt.x = w0; pkt.y = w1;
    *(uint2*)(orow + db * 16) = pkt;
  }
}

extern "C" void kernel_launch(void* const* d_in, const int* in_sizes, int n_in,
                              void* d_out, int out_size, void* d_ws, size_t ws_size,
                              hipStream_t stream) {
  const float* X  = (const float*)d_in[0];  // [2,2048,1024]
  const float* Wa = (const float*)d_in[1];  // [1024,3072]
  const float* ba = (const float*)d_in[2];  // [3072]
  const float* Wp = (const float*)d_in[3];  // [1024,1024]
  const float* bp = (const float*)d_in[4];  // [1024]
  float* out = (float*)d_out;               // [2,2048,1024] fp32

  char* ws = (char*)d_ws;
  bf16_t* Xb  = (bf16_t*)ws;                          // 8 MiB (reused as score)
  bf16_t* WaT = (bf16_t*)(ws + (size_t)(8u << 20));   // 6 MiB: W_attn^T [3072][1024]
  bf16_t* WpT = (bf16_t*)(ws + (size_t)(14u << 20));  // 2 MiB: W_proj^T [1024][1024]
  bf16_t* QKV = (bf16_t*)(ws + (size_t)(16u << 20));  // 24 MiB: [4096][3072]
  bf16_t* S_  = Xb;

  k_f32_to_bf16<<<2048, 256, 0, stream>>>(X, Xb, 4096 * 1024 / 8);
  k_transpose_bf16<<<dim3(48, 16), 256, 0, stream>>>(Wa, WaT, 1024, 3072);
  k_transpose_bf16<<<dim3(16, 16), 256, 0, stream>>>(Wp, WpT, 1024, 1024);
  // QKV: 128x128 tile, 512 threads, 2-phase dbuf -> 768 blocks = 3/CU
  k_gemm_bt<true, true, 128, 128, 512><<<768, 512, 0, stream>>>(Xb, WaT, ba, QKV, 4096, 3072, 1024, 24);
  k_attn<<<1024, 256, 0, stream>>>(QKV, S_);
  // proj: 64x64 tile, 256 threads, 2-phase dbuf -> 1024 blocks = 4/CU
  k_gemm_bt<false, false, 64, 64, 256><<<1024, 256, 0, stream>>>(S_, WpT, bp, out, 4096, 1024, 1024, 16);
}